// Round 13
// baseline (224.627 us; speedup 1.0000x reference)
//
#include <hip/hip_runtime.h>
#include <hip/hip_bf16.h>
#include <stdint.h>

// Shapes (fixed for this problem)
#define TOKENS 8192   // b*s = 4*2048
#define H 2048
#define JDIM 2048
#define NADAPT 64
#define RANK 16
#define KG 1024       // NADAPT*RANK
#define KTOT 3072     // H + KG
#define NT2 48        // gemm2 K-tiles = KTOT/64
#define NT1 64        // gemm1 K-tiles = H/32

typedef __bf16 v8bf __attribute__((ext_vector_type(8)));
typedef float v4f __attribute__((ext_vector_type(4)));
typedef float v16f __attribute__((ext_vector_type(16)));
typedef unsigned short us8 __attribute__((ext_vector_type(8)));
typedef unsigned short us4 __attribute__((ext_vector_type(4)));

__device__ __forceinline__ unsigned short f2bf(float f) {
  union { __bf16 b; unsigned short u; } c; c.b = (__bf16)f; return c.u;
}
__device__ __forceinline__ float bf2f(unsigned short u) {
  union { unsigned int u; float f; } c; c.u = ((unsigned int)u) << 16; return c.f;
}

__device__ __forceinline__ us8 pack8(float4 a, float4 b) {
  us8 r;
  r[0]=f2bf(a.x); r[1]=f2bf(a.y); r[2]=f2bf(a.z); r[3]=f2bf(a.w);
  r[4]=f2bf(b.x); r[5]=f2bf(b.y); r[6]=f2bf(b.z); r[7]=f2bf(b.w);
  return r;
}

__device__ __forceinline__ void split8(float4 a, float4 b, us8& h, us8& l) {
  float v[8] = {a.x, a.y, a.z, a.w, b.x, b.y, b.z, b.w};
  #pragma unroll
  for (int i = 0; i < 8; ++i) {
    h[i] = f2bf(v[i]);
    l[i] = f2bf(v[i] - bf2f(h[i]));
  }
}

// All input casts in one launch. Blocks [0,8192): x split -> XG hi + XLO;
// [8192,9216): A split -> Ahi/Alo; [9216,11264): W -> WB; [11264,11776): B -> WB.
__global__ void cast_all_kernel(const float* __restrict__ x,
                                const float* __restrict__ A,
                                const float* __restrict__ W,
                                const float* __restrict__ Bsrc,
                                unsigned short* __restrict__ XG,
                                unsigned short* __restrict__ XLO,
                                unsigned short* __restrict__ Ahi,
                                unsigned short* __restrict__ Alo,
                                unsigned short* __restrict__ WB) {
  int bid = blockIdx.x;
  int cg = threadIdx.x;
  if (bid < TOKENS) {                         // x rows
    int row = bid;
    const float4* s = (const float4*)(x + ((size_t)row << 11) + ((size_t)cg << 3));
    float4 a = s[0], b = s[1];
    us8 h, l;
    split8(a, b, h, l);
    *(us8*)(XG  + (size_t)row * KTOT + ((size_t)cg << 3)) = h;
    *(us8*)(XLO + (size_t)row * H    + ((size_t)cg << 3)) = l;
  } else if (bid < TOKENS + KG) {             // A rows
    int row = bid - TOKENS;
    const float4* s = (const float4*)(A + ((size_t)row << 11) + ((size_t)cg << 3));
    float4 a = s[0], b = s[1];
    us8 h, l;
    split8(a, b, h, l);
    *(us8*)(Ahi + ((size_t)row << 11) + ((size_t)cg << 3)) = h;
    *(us8*)(Alo + ((size_t)row << 11) + ((size_t)cg << 3)) = l;
  } else if (bid < TOKENS + KG + JDIM) {      // W rows
    int row = bid - TOKENS - KG;
    const float4* s = (const float4*)(W + ((size_t)row << 11) + ((size_t)cg << 3));
    float4 a = s[0], b = s[1];
    *(us8*)(WB + (size_t)row * KTOT + ((size_t)cg << 3)) = pack8(a, b);
  } else {                                    // B: one thread per (a,j)
    int idx = (bid - TOKENS - KG - JDIM) * 256 + cg;  // 131072 total
    int a = idx >> 11, j = idx & 2047;
    const float4* s = (const float4*)(Bsrc + (((size_t)a << 11) + j) * RANK);
    float4 f0 = s[0], f1 = s[1], f2 = s[2], f3 = s[3];
    us8* d = (us8*)(WB + (size_t)j * KTOT + H + a * RANK);
    d[0] = pack8(f0, f1);
    d[1] = pack8(f2, f3);
  }
}

// Per token: arrows = sumsq over r, top-4 adapters, G row = routes*v.
__global__ void route_kernel(const float* __restrict__ vecs,
                             unsigned short* __restrict__ XG) {
  __shared__ float vsh[4][16];
  int wave = threadIdx.x >> 6, lane = threadIdx.x & 63;
  int t = blockIdx.x * 4 + wave;
  const float* vrow = vecs + (size_t)t * KG;
  const float4* vp = (const float4*)(vrow + lane * RANK);
  float4 q0 = vp[0], q1 = vp[1], q2 = vp[2], q3 = vp[3];
  float ss = q0.x*q0.x + q0.y*q0.y + q0.z*q0.z + q0.w*q0.w
           + q1.x*q1.x + q1.y*q1.y + q1.z*q1.z + q1.w*q1.w
           + q2.x*q2.x + q2.y*q2.y + q2.z*q2.z + q2.w*q2.w
           + q3.x*q3.x + q3.y*q3.y + q3.z*q3.z + q3.w*q3.w;
  float arr = ss;
  int sel[4];
  #pragma unroll
  for (int k = 0; k < 4; ++k) {
    float m = arr; int mi = lane;
    #pragma unroll
    for (int o = 32; o > 0; o >>= 1) {
      float om = __shfl_xor(m, o);
      int oi  = __shfl_xor(mi, o);
      if (om > m || (om == m && oi < mi)) { m = om; mi = oi; }
    }
    sel[k] = mi;                 // wave-uniform
    if (lane == mi) arr = -3.0e38f;
  }
  if (lane < 16) {
    float s = vrow[sel[0]*RANK + lane] + vrow[sel[1]*RANK + lane]
            + vrow[sel[2]*RANK + lane] + vrow[sel[3]*RANK + lane];
    vsh[wave][lane] = 0.0625f * s;
  }
  __syncthreads();
  bool on = (lane == sel[0]) | (lane == sel[1]) | (lane == sel[2]) | (lane == sel[3]);
  us8 lo, hi;
  #pragma unroll
  for (int r = 0; r < 8; ++r) lo[r] = on ? f2bf(vsh[wave][r])     : (unsigned short)0;
  #pragma unroll
  for (int r = 0; r < 8; ++r) hi[r] = on ? f2bf(vsh[wave][r + 8]) : (unsigned short)0;
  us8* d = (us8*)(XG + (size_t)t * KTOT + H + lane * RANK);
  d[0] = lo; d[1] = hi;
}

__device__ __forceinline__ void gload_lds16(const void* gsrc, void* ldst) {
  __builtin_amdgcn_global_load_lds(
      (const __attribute__((address_space(1))) unsigned int*)gsrc,
      (__attribute__((address_space(3))) unsigned int*)ldst, 16, 0, 0);
}

// Shared schedule helpers
#define BAR()  asm volatile("s_waitcnt vmcnt(0) lgkmcnt(0)\n\ts_barrier" ::: "memory")  // prologue
#define BARO() asm volatile("s_barrier" ::: "memory")   // loop barrier
#define VM4() asm volatile("s_waitcnt vmcnt(4)" ::: "memory")
#define VM6() asm volatile("s_waitcnt vmcnt(6)" ::: "memory")
#define P1() __builtin_amdgcn_s_setprio(1)
#define P0() __builtin_amdgcn_s_setprio(0)

// ------------------------------------------------------------------
// GEMM1 (3-term split, read-ahead): vecs = Xhi@Ahi^T + Xhi@Alo^T + Xlo@Ahi^T.
// (round-11 version, known good)
// ------------------------------------------------------------------
#define MM1(mi, xf, bv) do {                                                   \
  acc[mi][0] = __builtin_amdgcn_mfma_f32_16x16x32_bf16(xf, bv[0], acc[mi][0], 0, 0, 0); \
  acc[mi][1] = __builtin_amdgcn_mfma_f32_16x16x32_bf16(xf, bv[1], acc[mi][1], 0, 0, 0); \
  acc[mi][2] = __builtin_amdgcn_mfma_f32_16x16x32_bf16(xf, bv[2], acc[mi][2], 0, 0, 0); \
  acc[mi][3] = __builtin_amdgcn_mfma_f32_16x16x32_bf16(xf, bv[3], acc[mi][3], 0, 0, 0); \
} while (0)

#define S_XH1(B, kel) gload_lds16(XhB + (size_t)srow * KTOT + (kel) + scol, (B) + tid*16)
#define S_XH2(B, kel) gload_lds16(XhB + (size_t)(srow + 128) * KTOT + (kel) + scol, (B) + 8192 + tid*16)
#define S_XL1(B, kel) gload_lds16(XlB + (size_t)srow * H + (kel) + scol, (B) + 16384 + tid*16)
#define S_XL2(B, kel) gload_lds16(XlB + (size_t)(srow + 128) * H + (kel) + scol, (B) + 24576 + tid*16)
#define S_AH1(B, kel) gload_lds16(AhB + (size_t)srow * H + (kel) + scol, (B) + 32768 + tid*16)
#define S_AL1(B, kel) gload_lds16(AlB + (size_t)srow * H + (kel) + scol, (B) + 40960 + tid*16)

#define TILE1(AHC, AHN, kel) do {                                              \
  P1(); MM1(0, xh[0], AHC); MM1(1, xh[1], AHC);                                \
        MM1(2, xh[2], AHC); MM1(3, xh[3], AHC); P0();                          \
  _Pragma("unroll")                                                            \
  for (int j = 0; j < 4; ++j) al[j] = *(const v8bf*)(bufA + 40960 + bbyte + j * 1024); \
  S_XH1(bufC, kel); S_XH2(bufC, kel);                                          \
  P1(); MM1(0, xh[0], al); MM1(1, xh[1], al);                                  \
        MM1(2, xh[2], al); MM1(3, xh[3], al); P0();                            \
  _Pragma("unroll")                                                            \
  for (int i = 0; i < 4; ++i) xl[i] = *(const v8bf*)(bufA + 16384 + abyte + i * 1024); \
  S_AH1(bufC, kel); S_XL1(bufC, kel);                                          \
  VM4(); BARO();                                                               \
  P1(); MM1(0, xl[0], AHC); MM1(1, xl[1], AHC);                                \
        MM1(2, xl[2], AHC); MM1(3, xl[3], AHC); P0();                          \
  _Pragma("unroll")                                                            \
  for (int i = 0; i < 4; ++i) xh[i] = *(const v8bf*)(bufB + abyte + i * 1024); \
  _Pragma("unroll")                                                            \
  for (int j = 0; j < 4; ++j) AHN[j] = *(const v8bf*)(bufB + 32768 + bbyte + j * 1024); \
  S_XL2(bufC, kel); S_AL1(bufC, kel);                                          \
  VM4(); BARO();                                                               \
  { char* tmp_ = bufA; bufA = bufB; bufB = bufC; bufC = tmp_; }                \
} while (0)

__global__ __launch_bounds__(512, 1) void gemm1_8ph_kernel(
    const unsigned short* __restrict__ Xhi,   // stride KTOT (hi block of XG)
    const unsigned short* __restrict__ Xlo,   // stride H
    const unsigned short* __restrict__ Ahi,   // stride H
    const unsigned short* __restrict__ Alo,   // stride H
    float* __restrict__ C) {                  // [8192][1024]
  __shared__ char Ls[147456];                 // 3 x 48KB
  const int tid = threadIdx.x;
  const int lane = tid & 63, wid = tid >> 6;
  const int wr = wid >> 1, wc = wid & 1;      // 4M x 2N waves, 64x64 each
  const int rA = lane & 15, grp = lane >> 4;
  const int grpx = (grp ^ ((rA >> 1) & 3)) << 4;

  const int bid = blockIdx.x;
  const int g = bid & 7, r = bid >> 3;
  const int bm = g * 4 + (r & 3), bn = r >> 2;  // bm-pinned per XCD

  const unsigned short* XhB = Xhi + (size_t)(bm * 256) * KTOT;
  const unsigned short* XlB = Xlo + (size_t)(bm * 256) * H;
  const unsigned short* AhB = Ahi + (size_t)(bn * 128) * H;
  const unsigned short* AlB = Alo + (size_t)(bn * 128) * H;

  const int srow = tid >> 2;
  const int scol = ((tid & 3) ^ ((tid >> 3) & 3)) << 3;   // pre-swizzled src slot

  const int abyte = (wr * 64 + rA) * 64 + grpx;   // within XH/XL (+mi*1024)
  const int bbyte = (wc * 64 + rA) * 64 + grpx;   // within AH/AL (+nj*1024)

  char* bufA = Ls;            // tile t (current reads)
  char* bufB = Ls + 49152;    // tile t+1
  char* bufC = Ls + 98304;    // tile t+2 (stage target)

  v4f acc[4][4];
  #pragma unroll
  for (int i = 0; i < 4; ++i)
    #pragma unroll
    for (int j = 0; j < 4; ++j)
      acc[i][j] = (v4f){0.f, 0.f, 0.f, 0.f};
  v8bf xh[4], xl[4], al[4], ahA[4], ahB_[4];

  // prologue: stage tiles 0 and 1 fully; full drain; preload p0 frags of tile 0
  S_XH1(bufA, 0); S_XH2(bufA, 0); S_AH1(bufA, 0); S_XL1(bufA, 0); S_XL2(bufA, 0); S_AL1(bufA, 0);
  S_XH1(bufB, 32); S_XH2(bufB, 32); S_AH1(bufB, 32); S_XL1(bufB, 32); S_XL2(bufB, 32); S_AL1(bufB, 32);
  BAR();
  #pragma unroll
  for (int i = 0; i < 4; ++i) xh[i] = *(const v8bf*)(bufA + abyte + i * 1024);
  #pragma unroll
  for (int j = 0; j < 4; ++j) ahA[j] = *(const v8bf*)(bufA + 32768 + bbyte + j * 1024);

  #pragma unroll 1
  for (int t = 0; t < NT1; t += 2) {
    const int ka = (t + 2 < NT1 ? t + 2 : NT1 - 1) * 32;
    const int kb = (t + 3 < NT1 ? t + 3 : NT1 - 1) * 32;
    TILE1(ahA, ahB_, ka);
    TILE1(ahB_, ahA, kb);
  }

  const int row0 = bm * 256 + wr * 64 + (grp << 2);
  const int col0 = bn * 128 + wc * 64 + rA;
  #pragma unroll
  for (int mi = 0; mi < 4; ++mi)
    #pragma unroll
    for (int j = 0; j < 4; ++j)
      #pragma unroll
      for (int q = 0; q < 4; ++q)
        C[(size_t)(row0 + mi * 16 + q) * KG + col0 + j * 16] = acc[mi][j][q];
}

// ------------------------------------------------------------------
// GEMM2 (round-10 schedule skeleton, 32x32x16 MFMA core):
// out = XG @ WB^T + bias. 256x256 tile, BK=64, 8 waves (2Mx4N, 128x64/wave).
// Per wave: 4 M-tiles x 2 N-tiles of 32x32, acc[4][2] f32x16.
// Frag layout (32x32x16): lane l reads 16B from row (l&31), k-slot 2*ks+(l>>5);
// existing (row>>1)&3 slot-swizzle keeps consecutive-8-lane groups on 8
// distinct bank-quads (conflict-free; staging unchanged).
// C/D: col=lane&31, row=(reg&3)+8*(reg>>2)+4*(lane>>5)  [m74/m101].
// Schedule: read-ahead (afA/afB, single bfr), STAGE 1 region + VM6 + barrier
// per phase -- exactly round 10's proven sequence.
// ------------------------------------------------------------------
#define STAGE(regionUS, panel, kelem) do {                                        \
  gload_lds16((panel) + aoff0 + (kelem), (char*)(regionUS) + tid * 16);           \
  gload_lds16((panel) + aoff1 + (kelem), (char*)(regionUS) + 8192 + tid * 16);    \
} while (0)

#define MM32(mi, nj, af_, bf_) \
  acc[mi][nj] = __builtin_amdgcn_mfma_f32_32x32x16_bf16(af_, bf_, acc[mi][nj], 0, 0, 0)

// frag index: af[mi'*2+ks], bfr[nj*2+ks]
#define AFRD(dst, R, mibase) do {                                                 \
  dst[0] = *(const v8bf*)((const char*)(R) + abase + (mibase)*2048 + psl0);       \
  dst[1] = *(const v8bf*)((const char*)(R) + abase + (mibase)*2048 + psl1);       \
  dst[2] = *(const v8bf*)((const char*)(R) + abase + (mibase+1)*2048 + psl0);     \
  dst[3] = *(const v8bf*)((const char*)(R) + abase + (mibase+1)*2048 + psl1);     \
} while (0)

#define BFRD(R) do {                                                              \
  bfr[0] = *(const v8bf*)((const char*)(R) + bbase + psl0);                       \
  bfr[1] = *(const v8bf*)((const char*)(R) + bbase + psl1);                       \
  bfr[2] = *(const v8bf*)((const char*)(R) + bbase + 2048 + psl0);                \
  bfr[3] = *(const v8bf*)((const char*)(R) + bbase + 2048 + psl1);                \
} while (0)

// odd phase: MFMA M-tiles 0,1 with afA x bfr; read afB <- RAn mh1; stage; VM6
#define PH2A(RAn, STG) do {                                                       \
  P1();                                                                           \
  MM32(0, 0, afA[0], bfr[0]); MM32(0, 1, afA[0], bfr[2]);                         \
  MM32(1, 0, afA[2], bfr[0]); MM32(1, 1, afA[2], bfr[2]);                         \
  MM32(0, 0, afA[1], bfr[1]); MM32(0, 1, afA[1], bfr[3]);                         \
  MM32(1, 0, afA[3], bfr[1]); MM32(1, 1, afA[3], bfr[3]);                         \
  P0();                                                                           \
  AFRD(afB, RAn, 2);                                                              \
  STG;                                                                            \
  VM6(); BARO();                                                                  \
} while (0)

// even phase: MFMA M-tiles 2,3 with afB x bfr; read bfr <- RBn, afA <- RAn mh0
#define PH2B(RBn, RAn, STG) do {                                                  \
  P1();                                                                           \
  MM32(2, 0, afB[0], bfr[0]); MM32(2, 1, afB[0], bfr[2]);                         \
  MM32(3, 0, afB[2], bfr[0]); MM32(3, 1, afB[2], bfr[2]);                         \
  MM32(2, 0, afB[1], bfr[1]); MM32(2, 1, afB[1], bfr[3]);                         \
  MM32(3, 0, afB[3], bfr[1]); MM32(3, 1, afB[3], bfr[3]);                         \
  P0();                                                                           \
  BFRD(RBn);                                                                      \
  AFRD(afA, RAn, 0);                                                              \
  STG;                                                                            \
  VM6(); BARO();                                                                  \
} while (0)

__global__ __launch_bounds__(512, 1) void gemm2_8ph_kernel(
    const unsigned short* __restrict__ Xg, const unsigned short* __restrict__ Wb,
    float* __restrict__ C, const float* __restrict__ bias) {
  __shared__ unsigned short lds[65536];   // 128 KB
  const int tid = threadIdx.x;
  const int lane = tid & 63, wid = tid >> 6;
  const int wr = wid >> 2, wc = wid & 3;

  const int l31 = lane & 31, hi5 = lane >> 5;
  const int xr = (l31 >> 1) & 3;
  const int psl0 = ((0 + hi5) ^ xr) << 4;   // ks=0: slot_log = hi5
  const int psl1 = ((2 + hi5) ^ xr) << 4;   // ks=1: slot_log = 2+hi5
  const int abase = (wr * 128 + l31) * 64;  // + mi*2048 per M-tile
  const int bbase = (wc * 64 + l31) * 64;   // + nj*2048 per N-tile

  const int bid = blockIdx.x;
  const int g = bid & 7, r = bid >> 3;
  const int bm = g * 4 + (r & 3), bn = r >> 2;     // bm-pinned per XCD

  const unsigned short* Ap = Xg + (size_t)(bm * 256) * KTOT;
  const unsigned short* Bp = Wb + (size_t)(bn * 256) * KTOT;

  const int srow = tid >> 2;
  const int scol = ((tid & 3) ^ ((tid >> 3) & 3)) << 3;
  const size_t aoff0 = (size_t)srow * KTOT + scol;
  const size_t aoff1 = (size_t)(srow + 128) * KTOT + scol;

  unsigned short* A0k0 = lds;
  unsigned short* A0k1 = lds + 8192;
  unsigned short* B0k0 = lds + 16384;
  unsigned short* B0k1 = lds + 24576;
  unsigned short* A1k0 = lds + 32768;
  unsigned short* A1k1 = lds + 40960;
  unsigned short* B1k0 = lds + 49152;
  unsigned short* B1k1 = lds + 57344;

  v16f acc[4][2];
  #pragma unroll
  for (int i = 0; i < 4; ++i)
    #pragma unroll
    for (int j = 0; j < 2; ++j)
      #pragma unroll
      for (int q = 0; q < 16; ++q)
        acc[i][j][q] = 0.f;
  v8bf afA[4], afB[4], bfr[4];

  // prologue: 6 regions; full drain; preload afA (A0k0 M-tiles 0,1) + bfr (B0k0)
  STAGE(A0k0, Ap, 0);
  STAGE(B0k0, Bp, 0);
  STAGE(A0k1, Ap, 32);
  STAGE(B0k1, Bp, 32);
  STAGE(A1k0, Ap, 64);
  STAGE(B1k0, Bp, 64);
  BAR();
  AFRD(afA, A0k0, 0);
  BFRD(B0k0);

  #pragma unroll 1
  for (int t = 0; t < NT2; t += 2) {
    const int k1a = (t + 1) * 64 + 32;
    const int k0a = (t + 2 < NT2 ? t + 2 : NT2 - 1) * 64;
    const int k1b = (t + 2 < NT2 ? t + 2 : NT2 - 1) * 64 + 32;
    const int k0b = (t + 3 < NT2 ? t + 3 : NT2 - 1) * 64;
    PH2A(A0k0, STAGE(A1k1, Ap, k1a));          // p1: A0k0/B0k0 M-tiles 0,1
    PH2B(B0k1, A0k1, STAGE(B1k1, Bp, k1a));    // p2: M-tiles 2,3; next B0k1/A0k1
    PH2A(A0k1, STAGE(A0k0, Ap, k0a));          // p3
    PH2B(B1k0, A1k0, STAGE(B0k0, Bp, k0a));    // p4
    PH2A(A1k0, STAGE(A0k1, Ap, k1b));          // p5
    PH2B(B1k1, A1k1, STAGE(B0k1, Bp, k1b));    // p6
    PH2A(A1k1, STAGE(A1k0, Ap, k0b));          // p7
    PH2B(B0k0, A0k0, STAGE(B1k0, Bp, k0b));    // p8
  }

  // epilogue: C/D 32x32 layout col=l31, row=(reg&3)+8*(reg>>2)+4*hi5
  const int row0 = bm * 256 + wr * 128 + (hi5 << 2);
  const int col0 = bn * 256 + wc * 64 + l31;
  float bv0 = bias[col0];
  float bv1 = bias[col0 + 32];
  #pragma unroll
  for (int mi = 0; mi < 4; ++mi)
    #pragma unroll
    for (int nj = 0; nj < 2; ++nj) {
      float bv = nj ? bv1 : bv0;
      #pragma unroll
      for (int reg = 0; reg < 16; ++reg) {
        int rr = row0 + mi * 32 + (reg & 3) + ((reg >> 2) << 3);
        C[(size_t)rr * JDIM + col0 + nj * 32] = acc[mi][nj][reg] + bv;
      }
    }
}

extern "C" void kernel_launch(void* const* d_in, const int* in_sizes, int n_in,
                              void* d_out, int out_size, void* d_ws, size_t ws_size,
                              hipStream_t stream) {
  const float* x    = (const float*)d_in[0];
  const float* A    = (const float*)d_in[1];
  const float* Bb   = (const float*)d_in[2];
  const float* W    = (const float*)d_in[3];
  const float* bias = (const float*)d_in[4];
  float* out = (float*)d_out;

  char* ws = (char*)d_ws;
  // ws layout: XG bf16 [8192][3072] (48M) | WB bf16 [2048][3072] (12M) |
  //            Ahi bf16 [1024][2048] (4M) | Alo bf16 [1024][2048] (4M)   = 68M
  unsigned short* XG  = (unsigned short*)ws;
  unsigned short* WB  = (unsigned short*)(ws + (size_t)48 * 1024 * 1024);
  unsigned short* Ahi = (unsigned short*)(ws + (size_t)60 * 1024 * 1024);
  unsigned short* Alo = (unsigned short*)(ws + (size_t)64 * 1024 * 1024);
  // d_out doubles as pre-gemm2 scratch: lower 32MB vecs f32, upper 32MB x_lo bf16.
  float* vecs         = (float*)d_out;
  unsigned short* XLO = (unsigned short*)((char*)d_out + (size_t)32 * 1024 * 1024);

  // all casts in one launch (x, A, W, B sections)
  cast_all_kernel<<<TOKENS + KG + JDIM + 512, 256, 0, stream>>>(
      x, A, W, Bb, XG, XLO, Ahi, Alo, WB);

  // vecs = x @ A^T in near-fp32 (3-term bf16 split), read-ahead pipeline
  gemm1_8ph_kernel<<<256, 512, 0, stream>>>(XG, XLO, Ahi, Alo, vecs);

  // routing -> G block of XG
  route_kernel<<<TOKENS / 4, 256, 0, stream>>>(vecs, XG);

  // out = [Xb|G] @ [Wb|Bt]^T + bias, 32x32x16 core on round-10 schedule
  gemm2_8ph_kernel<<<256, 512, 0, stream>>>(XG, WB, out, bias);
}

// Round 14
// 214.775 us; speedup vs baseline: 1.0459x; 1.0459x over previous
//
#include <hip/hip_runtime.h>
#include <hip/hip_bf16.h>
#include <stdint.h>

// Shapes (fixed for this problem)
#define TOKENS 8192   // b*s = 4*2048
#define H 2048
#define JDIM 2048
#define NADAPT 64
#define RANK 16
#define KG 1024       // NADAPT*RANK
#define KTOT 3072     // H + KG
#define NT2 48        // gemm2 K-tiles = KTOT/64
#define NT1 64        // gemm1 K-tiles = H/32

typedef __bf16 v8bf __attribute__((ext_vector_type(8)));
typedef float v4f __attribute__((ext_vector_type(4)));
typedef unsigned short us8 __attribute__((ext_vector_type(8)));
typedef unsigned short us4 __attribute__((ext_vector_type(4)));

__device__ __forceinline__ unsigned short f2bf(float f) {
  union { __bf16 b; unsigned short u; } c; c.b = (__bf16)f; return c.u;
}
__device__ __forceinline__ float bf2f(unsigned short u) {
  union { unsigned int u; float f; } c; c.u = ((unsigned int)u) << 16; return c.f;
}

__device__ __forceinline__ us8 pack8(float4 a, float4 b) {
  us8 r;
  r[0]=f2bf(a.x); r[1]=f2bf(a.y); r[2]=f2bf(a.z); r[3]=f2bf(a.w);
  r[4]=f2bf(b.x); r[5]=f2bf(b.y); r[6]=f2bf(b.z); r[7]=f2bf(b.w);
  return r;
}

__device__ __forceinline__ void split8(float4 a, float4 b, us8& h, us8& l) {
  float v[8] = {a.x, a.y, a.z, a.w, b.x, b.y, b.z, b.w};
  #pragma unroll
  for (int i = 0; i < 8; ++i) {
    h[i] = f2bf(v[i]);
    l[i] = f2bf(v[i] - bf2f(h[i]));
  }
}

// All input casts in one launch. Blocks [0,8192): x split -> XG hi + XLO;
// [8192,9216): A split -> Ahi/Alo; [9216,11264): W -> WB; [11264,11776): B -> WB.
__global__ void cast_all_kernel(const float* __restrict__ x,
                                const float* __restrict__ A,
                                const float* __restrict__ W,
                                const float* __restrict__ Bsrc,
                                unsigned short* __restrict__ XG,
                                unsigned short* __restrict__ XLO,
                                unsigned short* __restrict__ Ahi,
                                unsigned short* __restrict__ Alo,
                                unsigned short* __restrict__ WB) {
  int bid = blockIdx.x;
  int cg = threadIdx.x;
  if (bid < TOKENS) {                         // x rows
    int row = bid;
    const float4* s = (const float4*)(x + ((size_t)row << 11) + ((size_t)cg << 3));
    float4 a = s[0], b = s[1];
    us8 h, l;
    split8(a, b, h, l);
    *(us8*)(XG  + (size_t)row * KTOT + ((size_t)cg << 3)) = h;
    *(us8*)(XLO + (size_t)row * H    + ((size_t)cg << 3)) = l;
  } else if (bid < TOKENS + KG) {             // A rows
    int row = bid - TOKENS;
    const float4* s = (const float4*)(A + ((size_t)row << 11) + ((size_t)cg << 3));
    float4 a = s[0], b = s[1];
    us8 h, l;
    split8(a, b, h, l);
    *(us8*)(Ahi + ((size_t)row << 11) + ((size_t)cg << 3)) = h;
    *(us8*)(Alo + ((size_t)row << 11) + ((size_t)cg << 3)) = l;
  } else if (bid < TOKENS + KG + JDIM) {      // W rows
    int row = bid - TOKENS - KG;
    const float4* s = (const float4*)(W + ((size_t)row << 11) + ((size_t)cg << 3));
    float4 a = s[0], b = s[1];
    *(us8*)(WB + (size_t)row * KTOT + ((size_t)cg << 3)) = pack8(a, b);
  } else {                                    // B: one thread per (a,j)
    int idx = (bid - TOKENS - KG - JDIM) * 256 + cg;  // 131072 total
    int a = idx >> 11, j = idx & 2047;
    const float4* s = (const float4*)(Bsrc + (((size_t)a << 11) + j) * RANK);
    float4 f0 = s[0], f1 = s[1], f2 = s[2], f3 = s[3];
    us8* d = (us8*)(WB + (size_t)j * KTOT + H + a * RANK);
    d[0] = pack8(f0, f1);
    d[1] = pack8(f2, f3);
  }
}

// Per token: arrows = sumsq over r, top-4 adapters, G row = routes*v.
__global__ void route_kernel(const float* __restrict__ vecs,
                             unsigned short* __restrict__ XG) {
  __shared__ float vsh[4][16];
  int wave = threadIdx.x >> 6, lane = threadIdx.x & 63;
  int t = blockIdx.x * 4 + wave;
  const float* vrow = vecs + (size_t)t * KG;
  const float4* vp = (const float4*)(vrow + lane * RANK);
  float4 q0 = vp[0], q1 = vp[1], q2 = vp[2], q3 = vp[3];
  float ss = q0.x*q0.x + q0.y*q0.y + q0.z*q0.z + q0.w*q0.w
           + q1.x*q1.x + q1.y*q1.y + q1.z*q1.z + q1.w*q1.w
           + q2.x*q2.x + q2.y*q2.y + q2.z*q2.z + q2.w*q2.w
           + q3.x*q3.x + q3.y*q3.y + q3.z*q3.z + q3.w*q3.w;
  float arr = ss;
  int sel[4];
  #pragma unroll
  for (int k = 0; k < 4; ++k) {
    float m = arr; int mi = lane;
    #pragma unroll
    for (int o = 32; o > 0; o >>= 1) {
      float om = __shfl_xor(m, o);
      int oi  = __shfl_xor(mi, o);
      if (om > m || (om == m && oi < mi)) { m = om; mi = oi; }
    }
    sel[k] = mi;                 // wave-uniform
    if (lane == mi) arr = -3.0e38f;
  }
  if (lane < 16) {
    float s = vrow[sel[0]*RANK + lane] + vrow[sel[1]*RANK + lane]
            + vrow[sel[2]*RANK + lane] + vrow[sel[3]*RANK + lane];
    vsh[wave][lane] = 0.0625f * s;
  }
  __syncthreads();
  bool on = (lane == sel[0]) | (lane == sel[1]) | (lane == sel[2]) | (lane == sel[3]);
  us8 lo, hi;
  #pragma unroll
  for (int r = 0; r < 8; ++r) lo[r] = on ? f2bf(vsh[wave][r])     : (unsigned short)0;
  #pragma unroll
  for (int r = 0; r < 8; ++r) hi[r] = on ? f2bf(vsh[wave][r + 8]) : (unsigned short)0;
  us8* d = (us8*)(XG + (size_t)t * KTOT + H + lane * RANK);
  d[0] = lo; d[1] = hi;
}

__device__ __forceinline__ void gload_lds16(const void* gsrc, void* ldst) {
  __builtin_amdgcn_global_load_lds(
      (const __attribute__((address_space(1))) unsigned int*)gsrc,
      (__attribute__((address_space(3))) unsigned int*)ldst, 16, 0, 0);
}

// Shared schedule helpers
#define BAR()  asm volatile("s_waitcnt vmcnt(0) lgkmcnt(0)\n\ts_barrier" ::: "memory")  // prologue
#define BARO() asm volatile("s_barrier" ::: "memory")   // loop barrier
#define VM4() asm volatile("s_waitcnt vmcnt(4)" ::: "memory")
#define VM6() asm volatile("s_waitcnt vmcnt(6)" ::: "memory")
#define P1() __builtin_amdgcn_s_setprio(1)
#define P0() __builtin_amdgcn_s_setprio(0)

// ------------------------------------------------------------------
// GEMM1 (3-term split, read-ahead): vecs = Xhi@Ahi^T + Xhi@Alo^T + Xlo@Ahi^T.
// (round-11 version, best known)
// ------------------------------------------------------------------
#define MM1(mi, xf, bv) do {                                                   \
  acc[mi][0] = __builtin_amdgcn_mfma_f32_16x16x32_bf16(xf, bv[0], acc[mi][0], 0, 0, 0); \
  acc[mi][1] = __builtin_amdgcn_mfma_f32_16x16x32_bf16(xf, bv[1], acc[mi][1], 0, 0, 0); \
  acc[mi][2] = __builtin_amdgcn_mfma_f32_16x16x32_bf16(xf, bv[2], acc[mi][2], 0, 0, 0); \
  acc[mi][3] = __builtin_amdgcn_mfma_f32_16x16x32_bf16(xf, bv[3], acc[mi][3], 0, 0, 0); \
} while (0)

#define S_XH1(B, kel) gload_lds16(XhB + (size_t)srow * KTOT + (kel) + scol, (B) + tid*16)
#define S_XH2(B, kel) gload_lds16(XhB + (size_t)(srow + 128) * KTOT + (kel) + scol, (B) + 8192 + tid*16)
#define S_XL1(B, kel) gload_lds16(XlB + (size_t)srow * H + (kel) + scol, (B) + 16384 + tid*16)
#define S_XL2(B, kel) gload_lds16(XlB + (size_t)(srow + 128) * H + (kel) + scol, (B) + 24576 + tid*16)
#define S_AH1(B, kel) gload_lds16(AhB + (size_t)srow * H + (kel) + scol, (B) + 32768 + tid*16)
#define S_AL1(B, kel) gload_lds16(AlB + (size_t)srow * H + (kel) + scol, (B) + 40960 + tid*16)

#define TILE1(AHC, AHN, kel) do {                                              \
  P1(); MM1(0, xh[0], AHC); MM1(1, xh[1], AHC);                                \
        MM1(2, xh[2], AHC); MM1(3, xh[3], AHC); P0();                          \
  _Pragma("unroll")                                                            \
  for (int j = 0; j < 4; ++j) al[j] = *(const v8bf*)(bufA + 40960 + bbyte + j * 1024); \
  S_XH1(bufC, kel); S_XH2(bufC, kel);                                          \
  P1(); MM1(0, xh[0], al); MM1(1, xh[1], al);                                  \
        MM1(2, xh[2], al); MM1(3, xh[3], al); P0();                            \
  _Pragma("unroll")                                                            \
  for (int i = 0; i < 4; ++i) xl[i] = *(const v8bf*)(bufA + 16384 + abyte + i * 1024); \
  S_AH1(bufC, kel); S_XL1(bufC, kel);                                          \
  VM4(); BARO();                                                               \
  P1(); MM1(0, xl[0], AHC); MM1(1, xl[1], AHC);                                \
        MM1(2, xl[2], AHC); MM1(3, xl[3], AHC); P0();                          \
  _Pragma("unroll")                                                            \
  for (int i = 0; i < 4; ++i) xh[i] = *(const v8bf*)(bufB + abyte + i * 1024); \
  _Pragma("unroll")                                                            \
  for (int j = 0; j < 4; ++j) AHN[j] = *(const v8bf*)(bufB + 32768 + bbyte + j * 1024); \
  S_XL2(bufC, kel); S_AL1(bufC, kel);                                          \
  VM4(); BARO();                                                               \
  { char* tmp_ = bufA; bufA = bufB; bufB = bufC; bufC = tmp_; }                \
} while (0)

__global__ __launch_bounds__(512, 1) void gemm1_8ph_kernel(
    const unsigned short* __restrict__ Xhi,   // stride KTOT (hi block of XG)
    const unsigned short* __restrict__ Xlo,   // stride H
    const unsigned short* __restrict__ Ahi,   // stride H
    const unsigned short* __restrict__ Alo,   // stride H
    float* __restrict__ C) {                  // [8192][1024]
  __shared__ char Ls[147456];                 // 3 x 48KB
  const int tid = threadIdx.x;
  const int lane = tid & 63, wid = tid >> 6;
  const int wr = wid >> 1, wc = wid & 1;      // 4M x 2N waves, 64x64 each
  const int rA = lane & 15, grp = lane >> 4;
  const int grpx = (grp ^ ((rA >> 1) & 3)) << 4;

  const int bid = blockIdx.x;
  const int g = bid & 7, r = bid >> 3;
  const int bm = g * 4 + (r & 3), bn = r >> 2;  // bm-pinned per XCD

  const unsigned short* XhB = Xhi + (size_t)(bm * 256) * KTOT;
  const unsigned short* XlB = Xlo + (size_t)(bm * 256) * H;
  const unsigned short* AhB = Ahi + (size_t)(bn * 128) * H;
  const unsigned short* AlB = Alo + (size_t)(bn * 128) * H;

  const int srow = tid >> 2;
  const int scol = ((tid & 3) ^ ((tid >> 3) & 3)) << 3;   // pre-swizzled src slot

  const int abyte = (wr * 64 + rA) * 64 + grpx;   // within XH/XL (+mi*1024)
  const int bbyte = (wc * 64 + rA) * 64 + grpx;   // within AH/AL (+nj*1024)

  char* bufA = Ls;            // tile t (current reads)
  char* bufB = Ls + 49152;    // tile t+1
  char* bufC = Ls + 98304;    // tile t+2 (stage target)

  v4f acc[4][4];
  #pragma unroll
  for (int i = 0; i < 4; ++i)
    #pragma unroll
    for (int j = 0; j < 4; ++j)
      acc[i][j] = (v4f){0.f, 0.f, 0.f, 0.f};
  v8bf xh[4], xl[4], al[4], ahA[4], ahB_[4];

  // prologue: stage tiles 0 and 1 fully; full drain; preload p0 frags of tile 0
  S_XH1(bufA, 0); S_XH2(bufA, 0); S_AH1(bufA, 0); S_XL1(bufA, 0); S_XL2(bufA, 0); S_AL1(bufA, 0);
  S_XH1(bufB, 32); S_XH2(bufB, 32); S_AH1(bufB, 32); S_XL1(bufB, 32); S_XL2(bufB, 32); S_AL1(bufB, 32);
  BAR();
  #pragma unroll
  for (int i = 0; i < 4; ++i) xh[i] = *(const v8bf*)(bufA + abyte + i * 1024);
  #pragma unroll
  for (int j = 0; j < 4; ++j) ahA[j] = *(const v8bf*)(bufA + 32768 + bbyte + j * 1024);

  #pragma unroll 1
  for (int t = 0; t < NT1; t += 2) {
    const int ka = (t + 2 < NT1 ? t + 2 : NT1 - 1) * 32;
    const int kb = (t + 3 < NT1 ? t + 3 : NT1 - 1) * 32;
    TILE1(ahA, ahB_, ka);
    TILE1(ahB_, ahA, kb);
  }

  const int row0 = bm * 256 + wr * 64 + (grp << 2);
  const int col0 = bn * 128 + wc * 64 + rA;
  #pragma unroll
  for (int mi = 0; mi < 4; ++mi)
    #pragma unroll
    for (int j = 0; j < 4; ++j)
      #pragma unroll
      for (int q = 0; q < 4; ++q)
        C[(size_t)(row0 + mi * 16 + q) * KG + col0 + j * 16] = acc[mi][j][q];
}

// ------------------------------------------------------------------
// GEMM2 (round-10 best-known): out = XG @ WB^T + bias. 256x256, BK=64,
// 8 waves (2Mx4N), 16x16x32 core. Read-ahead: frag reads for phase p+1 issue
// during phase p (A double-buffered afA/afB, single bfr re-read on even
// phases). One STAGE (2 loads) + VM6 + barrier per phase. bm-pinned XCD map.
// ------------------------------------------------------------------
#define STAGE(regionUS, panel, kelem) do {                                        \
  gload_lds16((panel) + aoff0 + (kelem), (char*)(regionUS) + tid * 16);           \
  gload_lds16((panel) + aoff1 + (kelem), (char*)(regionUS) + 8192 + tid * 16);    \
} while (0)

// odd phase (mh0): MFMA acc[0..3] with AFC/bfr; read A mh1 rows of RAn into AFN
#define PH2A(AFC, RAn, AFN, STG) do {                                             \
  P1();                                                                           \
  _Pragma("unroll")                                                               \
  for (int i = 0; i < 4; ++i)                                                     \
    _Pragma("unroll")                                                             \
    for (int j = 0; j < 4; ++j)                                                   \
      acc[i][j] = __builtin_amdgcn_mfma_f32_16x16x32_bf16(                        \
          AFC[i], bfr[j], acc[i][j], 0, 0, 0);                                    \
  P0();                                                                           \
  _Pragma("unroll")                                                               \
  for (int i = 0; i < 4; ++i)                                                     \
    AFN[i] = *(const v8bf*)((const char*)(RAn) + abyte + (4 + i) * 1024);         \
  STG;                                                                            \
  VM6(); BARO();                                                                  \
} while (0)

// even phase (mh1): MFMA acc[4..7]; read B region RBn into bfr + A mh0 of RAn
#define PH2B(AFC, RBn, RAn, AFN, STG) do {                                        \
  P1();                                                                           \
  _Pragma("unroll")                                                               \
  for (int i = 0; i < 4; ++i)                                                     \
    _Pragma("unroll")                                                             \
    for (int j = 0; j < 4; ++j)                                                   \
      acc[4 + i][j] = __builtin_amdgcn_mfma_f32_16x16x32_bf16(                    \
          AFC[i], bfr[j], acc[4 + i][j], 0, 0, 0);                                \
  P0();                                                                           \
  _Pragma("unroll")                                                               \
  for (int j = 0; j < 4; ++j)                                                     \
    bfr[j] = *(const v8bf*)((const char*)(RBn) + bbyte + j * 1024);               \
  _Pragma("unroll")                                                               \
  for (int i = 0; i < 4; ++i)                                                     \
    AFN[i] = *(const v8bf*)((const char*)(RAn) + abyte + i * 1024);               \
  STG;                                                                            \
  VM6(); BARO();                                                                  \
} while (0)

__global__ __launch_bounds__(512, 1) void gemm2_8ph_kernel(
    const unsigned short* __restrict__ Xg, const unsigned short* __restrict__ Wb,
    float* __restrict__ C, const float* __restrict__ bias) {
  __shared__ unsigned short lds[65536];   // 128 KB
  const int tid = threadIdx.x;
  const int lane = tid & 63, wid = tid >> 6;
  const int wr = wid >> 2, wc = wid & 3;
  const int rA = lane & 15, grp = lane >> 4;
  const int grpx = (grp ^ ((rA >> 1) & 3)) << 4;   // swizzled 16B slot (byte)

  const int bid = blockIdx.x;
  const int g = bid & 7, r = bid >> 3;
  const int bm = g * 4 + (r & 3), bn = r >> 2;     // bm-pinned per XCD

  const unsigned short* Ap = Xg + (size_t)(bm * 256) * KTOT;
  const unsigned short* Bp = Wb + (size_t)(bn * 256) * KTOT;

  const int srow = tid >> 2;
  const int scol = ((tid & 3) ^ ((tid >> 3) & 3)) << 3;
  const size_t aoff0 = (size_t)srow * KTOT + scol;
  const size_t aoff1 = (size_t)(srow + 128) * KTOT + scol;

  unsigned short* A0k0 = lds;
  unsigned short* A0k1 = lds + 8192;
  unsigned short* B0k0 = lds + 16384;
  unsigned short* B0k1 = lds + 24576;
  unsigned short* A1k0 = lds + 32768;
  unsigned short* A1k1 = lds + 40960;
  unsigned short* B1k0 = lds + 49152;
  unsigned short* B1k1 = lds + 57344;

  const int abyte = (wr * 128 + rA) * 64 + grpx;
  const int bbyte = (wc * 64 + rA) * 64 + grpx;

  v4f acc[8][4];
  #pragma unroll
  for (int i = 0; i < 8; ++i)
    #pragma unroll
    for (int j = 0; j < 4; ++j)
      acc[i][j] = (v4f){0.f, 0.f, 0.f, 0.f};
  v8bf afA[4], afB[4], bfr[4];

  // prologue: 6 regions; full drain; preload afA (A0k0 mh0) + bfr (B0k0)
  STAGE(A0k0, Ap, 0);
  STAGE(B0k0, Bp, 0);
  STAGE(A0k1, Ap, 32);
  STAGE(B0k1, Bp, 32);
  STAGE(A1k0, Ap, 64);
  STAGE(B1k0, Bp, 64);
  BAR();
  #pragma unroll
  for (int i = 0; i < 4; ++i) afA[i] = *(const v8bf*)((const char*)A0k0 + abyte + i * 1024);
  #pragma unroll
  for (int j = 0; j < 4; ++j) bfr[j] = *(const v8bf*)((const char*)B0k0 + bbyte + j * 1024);

  #pragma unroll 1
  for (int t = 0; t < NT2; t += 2) {
    const int k1a = (t + 1) * 64 + 32;
    const int k0a = (t + 2 < NT2 ? t + 2 : NT2 - 1) * 64;
    const int k1b = (t + 2 < NT2 ? t + 2 : NT2 - 1) * 64 + 32;
    const int k0b = (t + 3 < NT2 ? t + 3 : NT2 - 1) * 64;
    PH2A(afA, A0k0, afB, STAGE(A1k1, Ap, k1a));          // p1: MFMA A0k0/B0k0 mh0
    PH2B(afB, B0k1, A0k1, afA, STAGE(B1k1, Bp, k1a));    // p2: mh1; read B0k1,A0k1mh0
    PH2A(afA, A0k1, afB, STAGE(A0k0, Ap, k0a));          // p3
    PH2B(afB, B1k0, A1k0, afA, STAGE(B0k0, Bp, k0a));    // p4
    PH2A(afA, A1k0, afB, STAGE(A0k1, Ap, k1b));          // p5
    PH2B(afB, B1k1, A1k1, afA, STAGE(B0k1, Bp, k1b));    // p6
    PH2A(afA, A1k1, afB, STAGE(A1k0, Ap, k0b));          // p7
    PH2B(afB, B0k0, A0k0, afA, STAGE(B1k0, Bp, k0b));    // p8
  }

  const int row0 = bm * 256 + wr * 128 + (grp << 2);
  const int col0 = bn * 256 + wc * 64 + rA;
  float bv[4];
  #pragma unroll
  for (int j = 0; j < 4; ++j) bv[j] = bias[col0 + j * 16];
  #pragma unroll
  for (int mi = 0; mi < 8; ++mi)
    #pragma unroll
    for (int j = 0; j < 4; ++j)
      #pragma unroll
      for (int q = 0; q < 4; ++q)
        C[(size_t)(row0 + mi * 16 + q) * JDIM + col0 + j * 16] = acc[mi][j][q] + bv[j];
}

extern "C" void kernel_launch(void* const* d_in, const int* in_sizes, int n_in,
                              void* d_out, int out_size, void* d_ws, size_t ws_size,
                              hipStream_t stream) {
  const float* x    = (const float*)d_in[0];
  const float* A    = (const float*)d_in[1];
  const float* Bb   = (const float*)d_in[2];
  const float* W    = (const float*)d_in[3];
  const float* bias = (const float*)d_in[4];
  float* out = (float*)d_out;

  char* ws = (char*)d_ws;
  // ws layout: XG bf16 [8192][3072] (48M) | WB bf16 [2048][3072] (12M) |
  //            Ahi bf16 [1024][2048] (4M) | Alo bf16 [1024][2048] (4M)   = 68M
  unsigned short* XG  = (unsigned short*)ws;
  unsigned short* WB  = (unsigned short*)(ws + (size_t)48 * 1024 * 1024);
  unsigned short* Ahi = (unsigned short*)(ws + (size_t)60 * 1024 * 1024);
  unsigned short* Alo = (unsigned short*)(ws + (size_t)64 * 1024 * 1024);
  // d_out doubles as pre-gemm2 scratch: lower 32MB vecs f32, upper 32MB x_lo bf16.
  float* vecs         = (float*)d_out;
  unsigned short* XLO = (unsigned short*)((char*)d_out + (size_t)32 * 1024 * 1024);

  // all casts in one launch (x, A, W, B sections)
  cast_all_kernel<<<TOKENS + KG + JDIM + 512, 256, 0, stream>>>(
      x, A, W, Bb, XG, XLO, Ahi, Alo, WB);

  // vecs = x @ A^T in near-fp32 (3-term bf16 split), read-ahead pipeline
  gemm1_8ph_kernel<<<256, 512, 0, stream>>>(XG, XLO, Ahi, Alo, vecs);

  // routing -> G block of XG
  route_kernel<<<TOKENS / 4, 256, 0, stream>>>(vecs, XG);

  // out = [Xb|G] @ [Wb|Bt]^T + bias, round-10 read-ahead 256² tile
  gemm2_8ph_kernel<<<256, 512, 0, stream>>>(XG, WB, out, bias);
}